// Round 1
// baseline (361.291 us; speedup 1.0000x reference)
//
#include <hip/hip_runtime.h>

#define N_POINTS 500000
#define N_W      128
#define N_OFF    50

// Kernel 1: accumulate Csum[w] = sum_n cos(2*pi*d_n/w) * tid[n,w]
//           Ssum[w] = sum_n sin(...) * tid[n,w]
// Layout: block = 256 threads; lane_w = t&31 indexes a float4 of wavelengths
// (w = 4*lane_w .. 4*lane_w+3), rg = t>>5 picks one of 8 consecutive rows per
// block iteration. Coalesced float4 loads: block iteration covers 8 rows x
// 128 w = 4 KB contiguous.
__global__ __launch_bounds__(256) void cs_accum(
    const float* __restrict__ xy,
    const float* __restrict__ tid,
    const float* __restrict__ center,
    const float* __restrict__ wavelength,
    float* __restrict__ sums)   // [0..127]=Csum, [128..255]=Ssum
{
    const int t = threadIdx.x;
    const int lane_w = t & 31;   // float4 column index
    const int rg     = t >> 5;   // 0..7 row-in-tile

    const float cx = center[0];
    const float cy = center[1];

    const float4 wl = ((const float4*)wavelength)[lane_w];
    float invw[4];
    invw[0] = 1.0f / wl.x;
    invw[1] = 1.0f / wl.y;
    invw[2] = 1.0f / wl.z;
    invw[3] = 1.0f / wl.w;

    float accC[4] = {0.f, 0.f, 0.f, 0.f};
    float accS[4] = {0.f, 0.f, 0.f, 0.f};

    // N_POINTS % 8 == 0, grid stride is a multiple of 8 -> exact coverage.
    for (int row0 = blockIdx.x * 8; row0 < N_POINTS; row0 += gridDim.x * 8) {
        const int row = row0 + rg;
        const float2 p = ((const float2*)xy)[row];
        const float dx = p.x - cx;
        const float dy = p.y - cy;
        const float d  = sqrtf(fmaf(dx, dx, dy * dy));

        const float4 v = ((const float4*)tid)[row * (N_W / 4) + lane_w];
        const float tv[4] = {v.x, v.y, v.z, v.w};

#pragma unroll
        for (int i = 0; i < 4; ++i) {
            // revolutions: phase/(2*pi) = d / wavelength
            float r = d * invw[i];
            r = r - floorf(r);                       // reduce for v_sin/v_cos
            const float s = __builtin_amdgcn_sinf(r); // sin(2*pi*r)
            const float c = __builtin_amdgcn_cosf(r); // cos(2*pi*r)
            accS[i] = fmaf(s, tv[i], accS[i]);
            accC[i] = fmaf(c, tv[i], accC[i]);
        }
    }

    // Block reduction over the 8 row-groups, then one atomic per (w, C/S).
    __shared__ float red[2][8][N_W];
    const int wbase = lane_w * 4;
#pragma unroll
    for (int i = 0; i < 4; ++i) {
        red[0][rg][wbase + i] = accC[i];
        red[1][rg][wbase + i] = accS[i];
    }
    __syncthreads();
    if (t < N_W) {
        float sc = 0.f, ss = 0.f;
#pragma unroll
        for (int g = 0; g < 8; ++g) {
            sc += red[0][g][t];
            ss += red[1][g][t];
        }
        atomicAdd(&sums[t], sc);
        atomicAdd(&sums[N_W + t], ss);
    }
}

// Kernel 2: C = Csum/N, S = Ssum/N; m[w] = max_j C*cos(o_j) - S*sin(o_j),
// o_j = 2*pi*j/49; out = -sum_w m[w].
__global__ __launch_bounds__(128) void finalize(
    const float* __restrict__ sums, float* __restrict__ out)
{
    __shared__ float red[N_W];
    const int w = threadIdx.x;
    const float invN = 1.0f / (float)N_POINTS;
    const float C = sums[w] * invN;
    const float S = sums[N_W + w] * invN;

    float m = -3.0e38f;
#pragma unroll
    for (int j = 0; j < N_OFF; ++j) {
        float rev = (float)j * (1.0f / 49.0f);  // offsets/(2*pi) = j/49
        rev = rev - floorf(rev);
        const float v = C * __builtin_amdgcn_cosf(rev)
                      - S * __builtin_amdgcn_sinf(rev);
        m = fmaxf(m, v);
    }
    red[w] = m;
    __syncthreads();
    for (int step = 64; step > 0; step >>= 1) {
        if (w < step) red[w] += red[w + step];
        __syncthreads();
    }
    if (w == 0) out[0] = -red[0];
}

extern "C" void kernel_launch(void* const* d_in, const int* in_sizes, int n_in,
                              void* d_out, int out_size, void* d_ws, size_t ws_size,
                              hipStream_t stream) {
    const float* xy         = (const float*)d_in[0];
    const float* tid        = (const float*)d_in[1];
    const float* center     = (const float*)d_in[2];
    const float* wavelength = (const float*)d_in[3];
    float* sums = (float*)d_ws;   // 256 floats = 1 KB
    float* out  = (float*)d_out;

    // ws is poisoned to 0xAA before every timed launch -> zero it each call.
    hipMemsetAsync(d_ws, 0, 2 * N_W * sizeof(float), stream);

    // 1024 blocks = 4 blocks/CU; 8 rows per block-iteration.
    cs_accum<<<1024, 256, 0, stream>>>(xy, tid, center, wavelength, sums);
    finalize<<<1, N_W, 0, stream>>>(sums, out);
}